// Round 6
// baseline (26.051 us; speedup 1.0000x reference)
//
#include <hip/hip_runtime.h>

// Problem constants (match the reference)
#define T_DIM 160
#define B_DIM 64
#define C_DIM 6625
#define S_DIM 25
#define L_DIM 51            // 2*S+1
#define J_DIM 26            // distinct class slots: blank + 25 labels
#define NEGV  (-1.0e30f)
#define LOG2E 1.4426950408889634f
#define LN2   0.6931471805599453f
#define CHUNK  32
#define NCHUNK (T_DIM / CHUNK)   // 5

// lane l gets x from lane l-1 via DPP wave_shr:1 (~5 cy vs ~35 cy ds_bpermute).
// Lane 0 receives `fill` through the DPP old-operand (bound_ctrl=0).
__device__ __forceinline__ float wave_shr1(float x, float fill) {
    return __int_as_float(__builtin_amdgcn_update_dpp(
        __float_as_int(fill), __float_as_int(x),
        0x138 /* wave_shr:1 */, 0xF, 0xF, false));
}

// One block per batch element.
//  wave 0: CTC alpha recurrence in log2 domain, lane l = lattice position.
//  waves 1..3: stage chunk c+1's dedup'd emissions (26 classes) into LDS
//  while wave 0 computes chunk c.
__global__ __launch_bounds__(256)
void ctc_alpha_fused(const float* __restrict__ preds,     // [T,B,C]
                     const int*   __restrict__ targets,   // [B,S]
                     const int*   __restrict__ tlen,      // [B]
                     float*       __restrict__ out)       // scalar (pre-zeroed)
{
    const int b   = blockIdx.x;
    const int tid = threadIdx.x;

    __shared__ float emit_s[T_DIM * J_DIM];   // 160*26*4 = 16640 B

    const size_t row = (size_t)B_DIM * C_DIM;
    const float* pb  = preds + (size_t)b * C_DIM;
    const int*   tg  = targets + b * S_DIM;

    // Prologue: stage chunk 0 with all 256 threads (26 distinct classes only).
    for (int f = tid; f < CHUNK * J_DIM; f += 256) {
        int t = f / J_DIM;
        int j = f - t * J_DIM;
        int cls = (j == 0) ? 0 : tg[j - 1];       // targets line is L1-hot
        emit_s[f] = pb[(size_t)t * row + cls] * LOG2E;
    }
    __syncthreads();

    // Per-lane recurrence constants (wave 0). Lanes 51..63 compute garbage
    // that stays finite and never flows downward (wave_shr only moves up).
    const int l = tid;
    const int j = (l < L_DIM) ? ((l & 1) ? (l >> 1) + 1 : 0) : 0;
    float mask3 = NEGV;                 // additive skip mask: 0 if skip allowed
    if (l < L_DIM && (l & 1) && l >= 3) {
        int i = l >> 1;
        if (tg[i] != tg[i - 1]) mask3 = 0.0f;
    }

    float alpha = NEGV;                 // log2-domain alpha
    if (l == 0) alpha = emit_s[0];      // t=0 blank slot
    if (l == 1) alpha = emit_s[1];      // t=0 first-label slot

    for (int c = 0; c < NCHUNK; ++c) {
        if (tid >= 64) {
            // Stage chunk c+1 while wave 0 computes chunk c.
            if (c + 1 < NCHUNK) {
                const int base = (c + 1) * CHUNK * J_DIM;
                const int t0   = (c + 1) * CHUNK;
                for (int f = tid - 64; f < CHUNK * J_DIM; f += 192) {
                    int tt = f / J_DIM;
                    int jj = f - tt * J_DIM;
                    int cls = (jj == 0) ? 0 : tg[jj - 1];
                    emit_s[base + f] =
                        pb[(size_t)(t0 + tt) * row + cls] * LOG2E;
                }
            }
        } else {
            const int cbase = c * CHUNK * J_DIM;
            #pragma unroll
            for (int k = 0; k < CHUNK; ++k) {
                if (c == 0 && k == 0) continue;          // t=0 is the init
                // emission read is alpha-independent: issues ahead of the chain
                float e  = emit_s[cbase + k * J_DIM + j];
                float a2 = wave_shr1(alpha, NEGV);       // alpha[l-1]
                float a3 = wave_shr1(a2, NEGV) + mask3;  // alpha[l-2] (masked)
                // max term contributes exp2(0)=1 exactly -> only 2 exps needed
                float m  = fmaxf(fmaxf(alpha, a2), a3);            // v_max3
                float md = __builtin_amdgcn_fmed3f(alpha, a2, a3); // v_med3
                float mn = fminf(fminf(alpha, a2), a3);            // v_min3
                float s  = 1.0f + __builtin_amdgcn_exp2f(md - m)
                                + __builtin_amdgcn_exp2f(mn - m);
                alpha = m + __builtin_amdgcn_logf(s) + e;
            }
        }
        __syncthreads();
    }

    // nll = -ln2 * log2addexp2(alpha[2*len], alpha[2*len-1])
    if (tid < 64) {
        const int len = tlen[b];
        const int idx = 2 * len;                         // in [10, 50]
        float l_last = __shfl(alpha, idx, 64);
        float l_prev = __shfl(alpha, idx - 1, 64);
        if (tid == 0) {
            float m   = fmaxf(l_last, l_prev);
            float r2  = m + __builtin_amdgcn_logf(
                             __builtin_amdgcn_exp2f(l_last - m)
                           + __builtin_amdgcn_exp2f(l_prev - m));
            float nll = -r2 * LN2;
            float per = (nll >= 1e29f) ? 0.0f : nll / (float)len;
            atomicAdd(out, per * (1.0f / B_DIM));
        }
    }
}

extern "C" void kernel_launch(void* const* d_in, const int* in_sizes, int n_in,
                              void* d_out, int out_size, void* d_ws, size_t ws_size,
                              hipStream_t stream)
{
    const float* preds   = (const float*)d_in[0];   // [T,B,C] fp32
    const int*   targets = (const int*)d_in[1];     // [B,S]
    const int*   tlen    = (const int*)d_in[2];     // [B]
    float* out = (float*)d_out;                     // scalar

    hipMemsetAsync(out, 0, sizeof(float), stream);  // out accumulates atomically
    ctc_alpha_fused<<<B_DIM, 256, 0, stream>>>(preds, targets, tlen, out);
}

// Round 7
// 20.625 us; speedup vs baseline: 1.2631x; 1.2631x over previous
//
#include <hip/hip_runtime.h>

// Problem constants (match the reference)
#define T_DIM 160
#define B_DIM 64
#define C_DIM 6625
#define S_DIM 25
#define L_DIM 51            // 2*S+1
#define J_DIM 26            // distinct class slots: blank + 25 labels
#define TJ    (T_DIM * J_DIM)        // 4160
#define NEGV  (-1.0e30f)
#define LOG2E 1.4426950408889634f
#define LN2   0.6931471805599453f
#define GCHUNK  16
#define NGCHUNK (T_DIM / GCHUNK)     // 10

// lane l gets x from lane l-1 via DPP wave_shr:1 (~5 cy vs ~35 cy ds_bpermute).
// Lane 0 receives `fill` through the DPP old-operand (bound_ctrl=0).
__device__ __forceinline__ float wave_shr1(float x, float fill) {
    return __int_as_float(__builtin_amdgcn_update_dpp(
        __float_as_int(fill), __float_as_int(x),
        0x138 /* wave_shr:1 */, 0xF, 0xF, false));
}

// ---------------------------------------------------------------------------
// Node 1: wide gather across all CUs. Block (b,c) fetches the 26 needed
// classes for t in [16c,16c+16), prescales by log2(e), writes emit_ws[b][t][26].
// Also zeroes the output scalar (node boundary orders this before node 2).
// ---------------------------------------------------------------------------
__global__ __launch_bounds__(256)
void ctc_gather(const float* __restrict__ preds,     // [T,B,C]
                const int*   __restrict__ targets,   // [B,S]
                float*       __restrict__ emit_ws,   // [B,T,26]
                float*       __restrict__ out)       // scalar, zeroed here
{
    const int b   = blockIdx.x;
    const int c   = blockIdx.y;
    const int tid = threadIdx.x;

    if (b == 0 && c == 0 && tid == 0) out[0] = 0.0f;

    __shared__ int cls_s[J_DIM];
    if (tid < J_DIM) cls_s[tid] = (tid == 0) ? 0 : targets[b * S_DIM + tid - 1];
    __syncthreads();

    const int t0 = c * GCHUNK;
    for (int f = tid; f < GCHUNK * J_DIM; f += 256) {
        int tl = f / J_DIM;
        int j  = f - tl * J_DIM;
        int t  = t0 + tl;
        float v = preds[((size_t)t * B_DIM + b) * C_DIM + cls_s[j]];
        emit_ws[(size_t)b * TJ + (size_t)t * J_DIM + j] = v * LOG2E;
    }
}

// ---------------------------------------------------------------------------
// Node 2: recurrence. One block per batch element; 256 threads burst the
// contiguous 16.6 KB slab into LDS, then wave 0 runs the 159-step alpha
// chain (lane l = lattice position, log2 domain, R5-proven form).
// ---------------------------------------------------------------------------
__global__ __launch_bounds__(256)
void ctc_alpha(const float* __restrict__ emit_ws,    // [B,T,26]
               const int*   __restrict__ targets,    // [B,S]
               const int*   __restrict__ tlen,       // [B]
               float*       __restrict__ out)        // scalar (zeroed by node 1)
{
    const int b   = blockIdx.x;
    const int tid = threadIdx.x;

    __shared__ float emit_s[TJ];                     // 16640 B

    // Contiguous burst: 1040 float4s over 256 threads.
    {
        const float4* src = (const float4*)(emit_ws + (size_t)b * TJ);
        float4*       dst = (float4*)emit_s;
        for (int i = tid; i < TJ / 4; i += 256) dst[i] = src[i];
    }
    __syncthreads();
    if (tid >= 64) return;                           // chain on wave 0 only

    const int  l      = tid;                         // lattice position
    const bool active = (l < L_DIM);
    const int  j      = active ? ((l & 1) ? (l >> 1) + 1 : 0) : 0;
    const int* tg     = targets + b * S_DIM;

    float mask3 = NEGV;                 // additive skip mask: 0 if skip allowed
    if (active && (l & 1) && l >= 3) {
        int i = l >> 1;
        if (tg[i] != tg[i - 1]) mask3 = 0.0f;
    }

    float alpha = NEGV;                 // log2-domain alpha
    if (l == 0) alpha = emit_s[0];      // t=0 blank slot
    if (l == 1) alpha = emit_s[1];      // t=0 first-label slot

    #pragma unroll 8
    for (int t = 1; t < T_DIM; ++t) {
        // emission read is alpha-independent: issues ahead of the chain
        float e  = active ? emit_s[t * J_DIM + j] : 0.0f;
        float a2 = wave_shr1(alpha, NEGV);       // alpha[l-1]
        float a3 = wave_shr1(a2, NEGV) + mask3;  // alpha[l-2] (masked)
        float m  = fmaxf(fmaxf(alpha, a2), a3);  // v_max3
        float s  = __builtin_amdgcn_exp2f(alpha - m)
                 + __builtin_amdgcn_exp2f(a2 - m)
                 + __builtin_amdgcn_exp2f(a3 - m);
        alpha = m + __builtin_amdgcn_logf(s) + e;
    }

    // nll = -ln2 * log2addexp2(alpha[2*len], alpha[2*len-1])
    const int len = tlen[b];
    const int idx = 2 * len;                         // in [10, 50]
    float l_last = __shfl(alpha, idx, 64);
    float l_prev = __shfl(alpha, idx - 1, 64);
    if (tid == 0) {
        float m   = fmaxf(l_last, l_prev);
        float r2  = m + __builtin_amdgcn_logf(
                         __builtin_amdgcn_exp2f(l_last - m)
                       + __builtin_amdgcn_exp2f(l_prev - m));
        float nll = -r2 * LN2;
        float per = (nll >= 1e29f) ? 0.0f : nll / (float)len;
        atomicAdd(out, per * (1.0f / B_DIM));
    }
}

// ---------------------------------------------------------------------------
// Fallback (R5-proven fused kernel) if ws is too small: 2 nodes incl. memset.
// ---------------------------------------------------------------------------
#define CHUNK  32
#define NCHUNK (T_DIM / CHUNK)   // 5
__global__ __launch_bounds__(256)
void ctc_alpha_fused(const float* __restrict__ preds,
                     const int*   __restrict__ targets,
                     const int*   __restrict__ tlen,
                     float*       __restrict__ out)
{
    const int b   = blockIdx.x;
    const int tid = threadIdx.x;
    __shared__ float emit_s[T_DIM * J_DIM];
    __shared__ int   cls_s[J_DIM];
    if (tid < J_DIM) cls_s[tid] = (tid == 0) ? 0 : targets[b * S_DIM + tid - 1];
    __syncthreads();
    const size_t row = (size_t)B_DIM * C_DIM;
    const float* pb  = preds + (size_t)b * C_DIM;
    for (int f = tid; f < CHUNK * J_DIM; f += 256) {
        int t = f / J_DIM;
        int j = f - t * J_DIM;
        emit_s[f] = pb[(size_t)t * row + cls_s[j]] * LOG2E;
    }
    __syncthreads();
    const int  l      = tid;
    const bool active = (l < L_DIM);
    const int  j      = active ? ((l & 1) ? (l >> 1) + 1 : 0) : 0;
    float mask3 = NEGV;
    if (active && (l & 1) && l >= 3) {
        int i = l >> 1;
        if (targets[b * S_DIM + i] != targets[b * S_DIM + i - 1]) mask3 = 0.0f;
    }
    float alpha = NEGV;
    if (l == 0) alpha = emit_s[0];
    if (l == 1) alpha = emit_s[1];
    for (int c = 0; c < NCHUNK; ++c) {
        if (tid >= 64) {
            if (c + 1 < NCHUNK) {
                const int base = (c + 1) * CHUNK * J_DIM;
                const int t0   = (c + 1) * CHUNK;
                for (int f = tid - 64; f < CHUNK * J_DIM; f += 192) {
                    int tt = f / J_DIM;
                    int jj = f - tt * J_DIM;
                    emit_s[base + f] =
                        pb[(size_t)(t0 + tt) * row + cls_s[jj]] * LOG2E;
                }
            }
        } else {
            const int cbase = c * CHUNK * J_DIM;
            #pragma unroll
            for (int k = 0; k < CHUNK; ++k) {
                if (c == 0 && k == 0) continue;
                float e  = active ? emit_s[cbase + k * J_DIM + j] : 0.0f;
                float a2 = wave_shr1(alpha, NEGV);
                float a3 = wave_shr1(a2, NEGV) + mask3;
                float m  = fmaxf(fmaxf(alpha, a2), a3);
                float s  = __builtin_amdgcn_exp2f(alpha - m)
                         + __builtin_amdgcn_exp2f(a2 - m)
                         + __builtin_amdgcn_exp2f(a3 - m);
                alpha = m + __builtin_amdgcn_logf(s) + e;
            }
        }
        __syncthreads();
    }
    if (tid < 64) {
        const int len = tlen[b];
        const int idx = 2 * len;
        float l_last = __shfl(alpha, idx, 64);
        float l_prev = __shfl(alpha, idx - 1, 64);
        if (tid == 0) {
            float m   = fmaxf(l_last, l_prev);
            float r2  = m + __builtin_amdgcn_logf(
                             __builtin_amdgcn_exp2f(l_last - m)
                           + __builtin_amdgcn_exp2f(l_prev - m));
            float nll = -r2 * LN2;
            float per = (nll >= 1e29f) ? 0.0f : nll / (float)len;
            atomicAdd(out, per * (1.0f / B_DIM));
        }
    }
}

extern "C" void kernel_launch(void* const* d_in, const int* in_sizes, int n_in,
                              void* d_out, int out_size, void* d_ws, size_t ws_size,
                              hipStream_t stream)
{
    const float* preds   = (const float*)d_in[0];   // [T,B,C] fp32
    const int*   targets = (const int*)d_in[1];     // [B,S]
    const int*   tlen    = (const int*)d_in[2];     // [B]
    float* out = (float*)d_out;                     // scalar

    const size_t ws_needed = (size_t)B_DIM * TJ * sizeof(float);
    if (ws_size >= ws_needed) {
        float* emit_ws = (float*)d_ws;
        dim3 ggrid(B_DIM, NGCHUNK);
        ctc_gather<<<ggrid, 256, 0, stream>>>(preds, targets, emit_ws, out);
        ctc_alpha<<<B_DIM, 256, 0, stream>>>(emit_ws, targets, tlen, out);
    } else {
        hipMemsetAsync(out, 0, sizeof(float), stream);
        ctc_alpha_fused<<<B_DIM, 256, 0, stream>>>(preds, targets, tlen, out);
    }
}